// Round 18
// baseline (219.004 us; speedup 1.0000x reference)
//
#include <hip/hip_runtime.h>
#include <math.h>

#define BB   512
#define CC   3
#define HH   64
#define WW   32
#define HOUT 38
#define WOUT 16
#define HID  128
#define DD   114               // CC*HOUT
#define SEQQ 36                // seq/h quarter stride (words)
#define SEQP 144               // 4*SEQQ
#define WIHP 132               // Wih LDS row pad (words); 132%32=4 -> banks spread
#define WHHP 132               // Whh LDS row pad (words)
#define NPOOL (CC*HOUT*WOUT)   // 1824

typedef float f32x4 __attribute__((ext_vector_type(4)));

// fast tanh on the serial chain: exact saturation at +/-inf, ~1e-6 abs error
__device__ __forceinline__ float fast_tanh(float u) {
    return 1.f - 2.f / (__expf(2.f * u) + 1.f);
}

// ws layout (bytes): t_mean floats [0, 262144); barrier counter at 262144
#define WS_CNT_OFF 262144

// ---- single fused kernel ---------------------------------------------------
// R13 compute body VERBATIM (512 blocks x 512 threads, 78.4 KB LDS ->
// 2 blocks/CU = 16 waves/CU; the proven-fast regime). After t_mean[b] is
// stored: R16-validated device-scope atomic barrier (exact-capacity grid:
// 512 = 2/CU x 256 CU, all blocks co-resident). Phase 2 = k2's proven
// pattern inlined: block b writes contiguous out[b,0,:,:] (256 KB stream)
// = s_mean_b (kept in LDS) * t_mean[:] (L2-warm).
__global__ __launch_bounds__(512, 4)
void k_fused(const float* __restrict__ x,
             const float* __restrict__ Wih,
             const float* __restrict__ Whh,
             const float* __restrict__ bih,
             const float* __restrict__ bhh,
             float* __restrict__ t_mean,
             int*   __restrict__ bar_cnt,
             f32x4* __restrict__ out)
{
    __shared__ __align__(16) float wst[HID * WHHP];  // 67.6 KB; x / Wih / Whh
    __shared__ __align__(16) float seq[WOUT][SEQP];  // 9.2 KB
    __shared__ __align__(16) float hbuf[2][SEQP];    // 1.2 KB
    __shared__ float red[8];
    __shared__ float sm_l;
    __shared__ int   rowl[HOUT];

    const int tid  = threadIdx.x;
    const int wid  = tid >> 6;                   // wave 0..7
    const int lane = tid & 63;
    const int kl   = (wid << 4) | (lane & 15);   // owned output row 0..127
    const int kc   = lane >> 4;                  // K-quarter 0..3
    const int b    = blockIdx.x;

    // --- issue x loads FIRST (oldest in vmcnt FIFO), then Wih prefetch ---
    f32x4 xpf[3];
    {
        const f32x4* xg = (const f32x4*)(x + (size_t)b * (CC*HH*WW));
        #pragma unroll
        for (int i = 0; i < 3; ++i) xpf[i] = xg[tid + 512*i];
    }
    f32x4 wihpf[7], wihtail;
    {
        const f32x4* wg = (const f32x4*)Wih;          // 3648 f4 total
        #pragma unroll
        for (int i = 0; i < 7; ++i) wihpf[i] = wg[tid + 512*i];
        if (tid < 64) wihtail = wg[3584 + tid];
    }

    // fractional-pool row starts (exact IEEE-f64 numpy match)
    if (tid < HOUT) {
        double alpha = (double)(HH - 2) / (double)(HOUT - 1);
        rowl[tid] = (tid < HOUT - 1)
            ? (int)(floor((tid + 0.5) * alpha) - floor(0.5 * alpha))
            : (HH - 2);
    }
    if (tid < HID) hbuf[0][SEQQ*(tid >> 5) + (tid & 31)] = 0.f;
    if (tid < 224) {                              // zero seq cols 114..127 (q3)
        int t = tid / 14, o = 18 + tid % 14;
        seq[t][3*SEQQ + o] = 0.f;
    }

    // --- write x to LDS (waits only on x loads; Wih stays in flight) ---
    {
        f32x4* xd = (f32x4*)wst;
        #pragma unroll
        for (int i = 0; i < 3; ++i) xd[tid + 512*i] = xpf[i];
    }
    __syncthreads();                                  // B1

    // --- pool (2x2 fractional max) + exact GELU -> seq; spatial sum ---
    float ps = 0.f;
    #pragma unroll
    for (int it = 0; it < 4; ++it) {
        int idx = tid + it*512;
        if (idx < NPOOL) {
            int c  = idx / (HOUT*WOUT);
            int r  = idx % (HOUT*WOUT);
            int ho = r / WOUT;
            int wo = r % WOUT;
            const float* p0 = &wst[c*(HH*WW) + rowl[ho]*WW + 2*wo];
            float m = fmaxf(fmaxf(p0[0], p0[1]), fmaxf(p0[WW], p0[WW+1]));
            ps += m;
            int d = c*HOUT + ho;
            seq[wo][SEQQ*(d >> 5) + (d & 31)] =
                0.5f * m * (1.f + erff(m * 0.70710678118654752440f));
        }
    }
    #pragma unroll
    for (int off = 32; off > 0; off >>= 1) ps += __shfl_down(ps, off);
    if (lane == 0) red[wid] = ps;
    __syncthreads();                                  // B2 (x reads done; wst reusable)
    if (tid == 0) {
        float r = 0.f;
        #pragma unroll
        for (int i = 0; i < 8; ++i) r += red[i];
        sm_l = r * (1.f / (float)NPOOL);
    }

    // --- Wih: LDS writes from prefetched regs into padded rows [128][132] ---
    #pragma unroll
    for (int i = 0; i < 7; ++i) {
        int j = 4*(tid + 512*i);
        #pragma unroll
        for (int e = 0; e < 4; ++e) {
            int r  = (j + e) / DD;                    // const-div -> magic mul
            int cc = (j + e) - r*DD;
            wst[r*WIHP + cc] = wihpf[i][e];
        }
    }
    if (tid < 64) {
        int j = 4*(3584 + tid);
        #pragma unroll
        for (int e = 0; e < 4; ++e) {
            int r  = (j + e) / DD;
            int cc = (j + e) - r*DD;
            wst[r*WIHP + cc] = wihtail[e];
        }
    }
    for (int j = tid; j < HID*14; j += 512)           // zero cols [114,128)
        wst[(j/14)*WIHP + DD + (j % 14)] = 0.f;
    __syncthreads();                                  // B3

    // wih regs: K-quarter kc of Wih row kl (32 floats)
    f32x4 wih[8];
    {
        const f32x4* wr = (const f32x4*)&wst[kl*WIHP + (kc << 5)];
        #pragma unroll
        for (int dd = 0; dd < 8; ++dd) wih[dd] = wr[dd];
    }

    // --- issue full Whh prefetch (8 f4); latency hides under projection ---
    f32x4 whhpf[8];
    {
        const f32x4* hg = (const f32x4*)Whh;          // 4096 f4
        #pragma unroll
        for (int i = 0; i < 8; ++i) whhpf[i] = hg[tid + 512*i];
    }

    // --- projection: zreg[t] complete in ALL lanes via 2-level shfl ---
    float zreg[WOUT];
    #pragma unroll
    for (int t = 0; t < WOUT; ++t) {
        const f32x4* a4 = (const f32x4*)&seq[t][kc*SEQQ];  // 4 bcast streams
        float s0 = 0.f, s1 = 0.f, s2 = 0.f, s3 = 0.f;
        #pragma unroll
        for (int dd = 0; dd < 8; ++dd) {
            f32x4 a = a4[dd], w = wih[dd];
            s0 = fmaf(w.x, a.x, s0);
            s1 = fmaf(w.y, a.y, s1);
            s2 = fmaf(w.z, a.z, s2);
            s3 = fmaf(w.w, a.w, s3);
        }
        float p = (s0 + s1) + (s2 + s3);
        p += __shfl_xor(p, 16);
        zreg[t] = p + __shfl_xor(p, 32);
    }
    {
        const float bias = bih[kl] + bhh[kl];
        #pragma unroll
        for (int t = 0; t < WOUT; ++t) zreg[t] += bias;
    }
    __syncthreads();                                  // B4 (wih copies done; wst free)

    // --- Whh: ONE staging round into padded rows [128][132] ---
    #pragma unroll
    for (int i = 0; i < 8; ++i) {
        int j4 = tid + 512*i;
        *(f32x4*)&wst[(j4 >> 5)*WHHP + ((j4 & 31) << 2)] = whhpf[i];
    }
    __syncthreads();                                  // B5
    f32x4 whh[8];
    {
        const f32x4* wr = (const f32x4*)&wst[kl*WHHP + (kc << 5)];
        #pragma unroll
        for (int dd = 0; dd < 8; ++dd) whh[dd] = wr[dd];
    }

    // --- 16-step recurrence: 2-shfl combine, ONE barrier/step ---
    float hsum = 0.f;
    #pragma unroll
    for (int t = 0; t < WOUT; ++t) {
        const int cur = t & 1, nxt = cur ^ 1;
        const f32x4* h4 = (const f32x4*)&hbuf[cur][kc*SEQQ];  // 4 bcast streams
        float s0 = 0.f, s1 = 0.f, s2 = 0.f, s3 = 0.f;
        #pragma unroll
        for (int dd = 0; dd < 8; ++dd) {
            f32x4 hv = h4[dd], w = whh[dd];
            s0 = fmaf(w.x, hv.x, s0);
            s1 = fmaf(w.y, hv.y, s1);
            s2 = fmaf(w.z, hv.z, s2);
            s3 = fmaf(w.w, hv.w, s3);
        }
        float p = (s0 + s1) + (s2 + s3);
        p += __shfl_xor(p, 16);
        float u  = zreg[t] + p + __shfl_xor(p, 32);
        float hn = fast_tanh(u);
        hsum += hn;
        if (kc == 0) hbuf[nxt][SEQQ*(kl >> 5) + (kl & 31)] = hn;
        __syncthreads();                              // h publish (one per step)
    }
    if (kc == 0) t_mean[b*HID + kl] = fast_tanh(hsum * (1.f / 16.f));

    // --- grid barrier (R16-validated; 512 blocks co-resident at 2/CU) ---
    __threadfence();                                  // release t_mean stores
    __syncthreads();
    if (tid == 0) {
        __hip_atomic_fetch_add(bar_cnt, 1, __ATOMIC_ACQ_REL,
                               __HIP_MEMORY_SCOPE_AGENT);
        long iters = 0;
        while (__hip_atomic_load(bar_cnt, __ATOMIC_ACQUIRE,
                                 __HIP_MEMORY_SCOPE_AGENT) < BB
               && iters < 20000000L) {
            __builtin_amdgcn_s_sleep(8);
            ++iters;                                  // bounded spin: hang-guard
        }
    }
    __syncthreads();
    __threadfence();                                  // acquire: drop stale lines

    // --- phase 2 (k2's proven pattern): contiguous 256 KB row stream ---
    {
        const float  s  = sm_l;
        const f32x4* t4 = (const f32x4*)t_mean;       // 16384 f4, L2-warm
        f32x4*       o  = out + (size_t)b * 16384;
        #pragma unroll
        for (int j = 0; j < 32; ++j) {
            int idx = tid + 512*j;
            o[idx] = s * t4[idx];
        }
    }
}

extern "C" void kernel_launch(void* const* d_in, const int* in_sizes, int n_in,
                              void* d_out, int out_size, void* d_ws, size_t ws_size,
                              hipStream_t stream)
{
    const float* x   = (const float*)d_in[0];
    const float* Wih = (const float*)d_in[1];
    const float* Whh = (const float*)d_in[2];
    const float* bih = (const float*)d_in[3];
    const float* bhh = (const float*)d_in[4];

    float* t_mean  = (float*)d_ws;
    int*   bar_cnt = (int*)((char*)d_ws + WS_CNT_OFF);

    hipMemsetAsync(bar_cnt, 0, sizeof(int), stream);  // zero barrier each call
    k_fused<<<dim3(BB), dim3(512), 0, stream>>>(
        x, Wih, Whh, bih, bhh, t_mean, bar_cnt, (f32x4*)d_out);
}

// Round 19
// 49.854 us; speedup vs baseline: 4.3929x; 4.3929x over previous
//
#include <hip/hip_runtime.h>
#include <math.h>

#define BB   512
#define CC   3
#define HH   64
#define WW   32
#define HOUT 38
#define WOUT 16
#define HID  128
#define DD   114               // CC*HOUT
#define SEQQ 36                // seq/h quarter stride (words)
#define SEQP 144               // 4*SEQQ
#define WIHP 132               // Wih LDS row pad (words); 132%32=4 -> banks spread
#define WHHP 132               // Whh LDS row pad (words)
#define NPOOL (CC*HOUT*WOUT)   // 1824

typedef float f32x4 __attribute__((ext_vector_type(4)));

// fast tanh on the serial chain: exact saturation at +/-inf, ~1e-6 abs error
__device__ __forceinline__ float fast_tanh(float u) {
    return 1.f - 2.f / (__expf(2.f * u) + 1.f);
}

// ws layout (floats)
#define WS_SMEAN 0
#define WS_TMEAN 512

// ---- fused per-batch kernel (R13-proven: 48.48 us total) -------------------
// 512 blocks x 512 threads (8 waves), 78.3 KB LDS -> 2 blocks/CU. Wave w owns
// rows [16w,16w+16); lane l: kl = 16w+(l&15), kc = l>>4 is the K-quarter.
// Split-K partials combine via shfl_xor(16)+shfl_xor(32); ONE barrier/step.
__global__ __launch_bounds__(512, 4)
void k1_fused(const float* __restrict__ x,
              const float* __restrict__ Wih,
              const float* __restrict__ Whh,
              const float* __restrict__ bih,
              const float* __restrict__ bhh,
              float* __restrict__ s_mean,
              float* __restrict__ t_mean)
{
    __shared__ __align__(16) float wst[HID * WHHP];  // 67.6 KB; x / Wih / Whh
    __shared__ __align__(16) float seq[WOUT][SEQP];  // 9.2 KB
    __shared__ __align__(16) float hbuf[2][SEQP];    // 1.2 KB
    __shared__ float red[8];
    __shared__ int   rowl[HOUT];

    const int tid  = threadIdx.x;
    const int wid  = tid >> 6;                   // wave 0..7
    const int lane = tid & 63;
    const int kl   = (wid << 4) | (lane & 15);   // owned output row 0..127
    const int kc   = lane >> 4;                  // K-quarter 0..3
    const int b    = blockIdx.x;

    // --- issue x loads FIRST (oldest in vmcnt FIFO), then Wih prefetch ---
    f32x4 xpf[3];
    {
        const f32x4* xg = (const f32x4*)(x + (size_t)b * (CC*HH*WW));
        #pragma unroll
        for (int i = 0; i < 3; ++i) xpf[i] = xg[tid + 512*i];
    }
    f32x4 wihpf[7], wihtail;
    {
        const f32x4* wg = (const f32x4*)Wih;          // 3648 f4 total
        #pragma unroll
        for (int i = 0; i < 7; ++i) wihpf[i] = wg[tid + 512*i];
        if (tid < 64) wihtail = wg[3584 + tid];
    }

    // fractional-pool row starts (exact IEEE-f64 numpy match)
    if (tid < HOUT) {
        double alpha = (double)(HH - 2) / (double)(HOUT - 1);
        rowl[tid] = (tid < HOUT - 1)
            ? (int)(floor((tid + 0.5) * alpha) - floor(0.5 * alpha))
            : (HH - 2);
    }
    if (tid < HID) hbuf[0][SEQQ*(tid >> 5) + (tid & 31)] = 0.f;
    if (tid < 224) {                              // zero seq cols 114..127 (q3)
        int t = tid / 14, o = 18 + tid % 14;
        seq[t][3*SEQQ + o] = 0.f;
    }

    // --- write x to LDS (waits only on x loads; Wih stays in flight) ---
    {
        f32x4* xd = (f32x4*)wst;
        #pragma unroll
        for (int i = 0; i < 3; ++i) xd[tid + 512*i] = xpf[i];
    }
    __syncthreads();                                  // B1

    // --- pool (2x2 fractional max) + exact GELU -> seq; spatial sum ---
    float ps = 0.f;
    #pragma unroll
    for (int it = 0; it < 4; ++it) {
        int idx = tid + it*512;
        if (idx < NPOOL) {
            int c  = idx / (HOUT*WOUT);
            int r  = idx % (HOUT*WOUT);
            int ho = r / WOUT;
            int wo = r % WOUT;
            const float* p0 = &wst[c*(HH*WW) + rowl[ho]*WW + 2*wo];
            float m = fmaxf(fmaxf(p0[0], p0[1]), fmaxf(p0[WW], p0[WW+1]));
            ps += m;
            int d = c*HOUT + ho;
            seq[wo][SEQQ*(d >> 5) + (d & 31)] =
                0.5f * m * (1.f + erff(m * 0.70710678118654752440f));
        }
    }
    #pragma unroll
    for (int off = 32; off > 0; off >>= 1) ps += __shfl_down(ps, off);
    if (lane == 0) red[wid] = ps;
    __syncthreads();                                  // B2 (x reads done; wst reusable)
    if (tid == 0) {
        float r = 0.f;
        #pragma unroll
        for (int i = 0; i < 8; ++i) r += red[i];
        s_mean[b] = r * (1.f / (float)NPOOL);
    }

    // --- Wih: LDS writes from prefetched regs into padded rows [128][132] ---
    #pragma unroll
    for (int i = 0; i < 7; ++i) {
        int j = 4*(tid + 512*i);
        #pragma unroll
        for (int e = 0; e < 4; ++e) {
            int r  = (j + e) / DD;                    // const-div -> magic mul
            int cc = (j + e) - r*DD;
            wst[r*WIHP + cc] = wihpf[i][e];
        }
    }
    if (tid < 64) {
        int j = 4*(3584 + tid);
        #pragma unroll
        for (int e = 0; e < 4; ++e) {
            int r  = (j + e) / DD;
            int cc = (j + e) - r*DD;
            wst[r*WIHP + cc] = wihtail[e];
        }
    }
    for (int j = tid; j < HID*14; j += 512)           // zero cols [114,128)
        wst[(j/14)*WIHP + DD + (j % 14)] = 0.f;
    __syncthreads();                                  // B3

    // wih regs: K-quarter kc of Wih row kl (32 floats)
    f32x4 wih[8];
    {
        const f32x4* wr = (const f32x4*)&wst[kl*WIHP + (kc << 5)];
        #pragma unroll
        for (int dd = 0; dd < 8; ++dd) wih[dd] = wr[dd];
    }

    // --- issue full Whh prefetch (8 f4); latency hides under projection ---
    f32x4 whhpf[8];
    {
        const f32x4* hg = (const f32x4*)Whh;          // 4096 f4
        #pragma unroll
        for (int i = 0; i < 8; ++i) whhpf[i] = hg[tid + 512*i];
    }

    // --- projection: zreg[t] complete in ALL lanes via 2-level shfl ---
    float zreg[WOUT];
    #pragma unroll
    for (int t = 0; t < WOUT; ++t) {
        const f32x4* a4 = (const f32x4*)&seq[t][kc*SEQQ];  // 4 bcast streams
        float s0 = 0.f, s1 = 0.f, s2 = 0.f, s3 = 0.f;
        #pragma unroll
        for (int dd = 0; dd < 8; ++dd) {
            f32x4 a = a4[dd], w = wih[dd];
            s0 = fmaf(w.x, a.x, s0);
            s1 = fmaf(w.y, a.y, s1);
            s2 = fmaf(w.z, a.z, s2);
            s3 = fmaf(w.w, a.w, s3);
        }
        float p = (s0 + s1) + (s2 + s3);
        p += __shfl_xor(p, 16);
        zreg[t] = p + __shfl_xor(p, 32);
    }
    {
        const float bias = bih[kl] + bhh[kl];
        #pragma unroll
        for (int t = 0; t < WOUT; ++t) zreg[t] += bias;
    }
    __syncthreads();                                  // B4 (wih copies done; wst free)

    // --- Whh: ONE staging round into padded rows [128][132] ---
    #pragma unroll
    for (int i = 0; i < 8; ++i) {
        int j4 = tid + 512*i;
        *(f32x4*)&wst[(j4 >> 5)*WHHP + ((j4 & 31) << 2)] = whhpf[i];
    }
    __syncthreads();                                  // B5
    f32x4 whh[8];
    {
        const f32x4* wr = (const f32x4*)&wst[kl*WHHP + (kc << 5)];
        #pragma unroll
        for (int dd = 0; dd < 8; ++dd) whh[dd] = wr[dd];
    }

    // --- 16-step recurrence: 2-shfl combine, ONE barrier/step ---
    float hsum = 0.f;
    #pragma unroll
    for (int t = 0; t < WOUT; ++t) {
        const int cur = t & 1, nxt = cur ^ 1;
        const f32x4* h4 = (const f32x4*)&hbuf[cur][kc*SEQQ];  // 4 bcast streams
        float s0 = 0.f, s1 = 0.f, s2 = 0.f, s3 = 0.f;
        #pragma unroll
        for (int dd = 0; dd < 8; ++dd) {
            f32x4 hv = h4[dd], w = whh[dd];
            s0 = fmaf(w.x, hv.x, s0);
            s1 = fmaf(w.y, hv.y, s1);
            s2 = fmaf(w.z, hv.z, s2);
            s3 = fmaf(w.w, hv.w, s3);
        }
        float p = (s0 + s1) + (s2 + s3);
        p += __shfl_xor(p, 16);
        float u  = zreg[t] + p + __shfl_xor(p, 32);
        float hn = fast_tanh(u);
        hsum += hn;
        if (kc == 0) hbuf[nxt][SEQQ*(kl >> 5) + (kl & 31)] = hn;
        __syncthreads();                              // h publish (one per step)
    }
    if (kc == 0) t_mean[b*HID + kl] = fast_tanh(hsum * (1.f / 16.f));
}

// ---- k2: block (i, sub) writes out[i, 0, sub*2048 .. +2048) f4 -------------
// nt stores: don't write-allocate 134 MB through L2; keep t_mean resident.
__global__ __launch_bounds__(256)
void k2_out(const float* __restrict__ s_mean,
            const float* __restrict__ t_mean,
            f32x4* __restrict__ out)
{
    const int i   = blockIdx.x >> 3;           // batch row (512)
    const int sub = blockIdx.x & 7;            // eighth of a row
    const float s = s_mean[i];
    const f32x4* t4 = (const f32x4*)t_mean + sub*2048;
    f32x4*       o  = out + (size_t)i*16384 + sub*2048;
    const int tid = threadIdx.x;
    #pragma unroll
    for (int j = 0; j < 8; ++j) {
        int idx = tid + j*256;
        f32x4 v = s * t4[idx];
        __builtin_nontemporal_store(v, &o[idx]);
    }
}

extern "C" void kernel_launch(void* const* d_in, const int* in_sizes, int n_in,
                              void* d_out, int out_size, void* d_ws, size_t ws_size,
                              hipStream_t stream)
{
    const float* x   = (const float*)d_in[0];
    const float* Wih = (const float*)d_in[1];
    const float* Whh = (const float*)d_in[2];
    const float* bih = (const float*)d_in[3];
    const float* bhh = (const float*)d_in[4];

    float* ws     = (float*)d_ws;
    float* s_mean = ws + WS_SMEAN;
    float* t_mean = ws + WS_TMEAN;

    k1_fused<<<dim3(BB), dim3(512), 0, stream>>>(x, Wih, Whh, bih, bhh, s_mean, t_mean);
    k2_out  <<<dim3(4096), dim3(256), 0, stream>>>(s_mean, t_mean, (f32x4*)d_out);
}